// Round 1
// baseline (500.645 us; speedup 1.0000x reference)
//
#include <hip/hip_runtime.h>
#include <math.h>

// GMRF sampling loss. Scalar output.
// N = 100000 nodes, E = 1.6M edges, D_MEAN = 32, RANK = 16, BETA = 1.0.
// Pipeline: deg histogram -> dinv -> {node SS, Gram, edge reductions} -> final
// All reductions accumulate in double (scalar threshold 0.18 needs better than
// fp32 over 3.2M-term sums); one double atomicAdd per block.

#define NTHR 256

__device__ __forceinline__ double blk_reduce(double v, double* sm) {
    // wave64 shuffle reduce, then cross-wave via LDS
    #pragma unroll
    for (int o = 32; o > 0; o >>= 1) v += __shfl_down(v, o, 64);
    const int lane = threadIdx.x & 63;
    const int wid  = threadIdx.x >> 6;
    __syncthreads();               // protect sm reuse across calls
    if (lane == 0) sm[wid] = v;
    __syncthreads();
    double s = 0.0;
    if (threadIdx.x == 0) {
        const int nw = blockDim.x >> 6;
        for (int i = 0; i < nw; i++) s += sm[i];
    }
    return s;
}

__global__ void deg_kernel(const int* __restrict__ row, int* __restrict__ deg, int E) {
    for (int e = blockIdx.x * blockDim.x + threadIdx.x; e < E; e += gridDim.x * blockDim.x)
        atomicAdd(&deg[row[e]], 1);
}

__global__ void dinv_kernel(const int* __restrict__ deg, float* __restrict__ dinv, int N) {
    for (int n = blockIdx.x * blockDim.x + threadIdx.x; n < N; n += gridDim.x * blockDim.x) {
        int d = deg[n];
        dinv[n] = (d > 0) ? (float)(1.0 / sqrt((double)d)) : 0.0f;
    }
}

// acc layout: [0]=SS_mean [1]=S_edge_mean [2]=SS_std [3]=S_edge_std [4]=S_selfloop
__global__ void ss_kernel(const float* __restrict__ zm, const float* __restrict__ zs,
                          double* __restrict__ acc, int N) {
    double pm = 0.0, ps = 0.0;
    for (int n = blockIdx.x * blockDim.x + threadIdx.x; n < N; n += gridDim.x * blockDim.x) {
        const float4* a = (const float4*)(zm + (size_t)n * 32);
        #pragma unroll
        for (int i = 0; i < 8; i++) {
            float4 v = a[i];
            pm += (double)(v.x * v.x + v.y * v.y) + (double)(v.z * v.z + v.w * v.w);
        }
        const float4* b = (const float4*)(zs + (size_t)n * 16);
        #pragma unroll
        for (int i = 0; i < 4; i++) {
            float4 v = b[i];
            ps += (double)(v.x * v.x + v.y * v.y) + (double)(v.z * v.z + v.w * v.w);
        }
    }
    __shared__ double sm[NTHR / 64];
    double t;
    t = blk_reduce(pm, sm); if (threadIdx.x == 0) atomicAdd(&acc[0], t);
    t = blk_reduce(ps, sm); if (threadIdx.x == 0) atomicAdd(&acc[2], t);
}

// Gram: block -> (pair p, row-chunk). 136 upper-triangle pairs of a 16x16.
#define NPAIR 136
#define GCHUNK 8
__global__ void gram_kernel(const float* __restrict__ zs, double* __restrict__ G, int N) {
    const int p     = blockIdx.x % NPAIR;
    const int chunk = blockIdx.x / NPAIR;
    int i = 0, pp = p;
    while (pp >= 16 - i) { pp -= 16 - i; i++; }
    const int j = i + pp;
    const int per = (N + GCHUNK - 1) / GCHUNK;
    const int n0 = chunk * per;
    const int n1 = (n0 + per < N) ? (n0 + per) : N;
    double a = 0.0;
    for (int n = n0 + threadIdx.x; n < n1; n += blockDim.x)
        a += (double)zs[(size_t)n * 16 + i] * (double)zs[(size_t)n * 16 + j];
    __shared__ double sm[NTHR / 64];
    double t = blk_reduce(a, sm);
    if (threadIdx.x == 0) atomicAdd(&G[i * 16 + j], t);
}

__global__ void edge_kernel(const float* __restrict__ zm, const float* __restrict__ zs,
                            const int* __restrict__ row, const int* __restrict__ col,
                            const float* __restrict__ dinv, double* __restrict__ acc, int E) {
    double pm = 0.0, ps = 0.0, psl = 0.0;
    for (int e = blockIdx.x * blockDim.x + threadIdx.x; e < E; e += gridDim.x * blockDim.x) {
        const int r = row[e], c = col[e];
        const float w = dinv[r] * dinv[c];
        const float4* ar = (const float4*)(zm + (size_t)r * 32);
        const float4* ac = (const float4*)(zm + (size_t)c * 32);
        float dm = 0.0f;
        #pragma unroll
        for (int i = 0; i < 8; i++) {
            float4 a = ar[i], b = ac[i];
            dm += a.x * b.x + a.y * b.y + a.z * b.z + a.w * b.w;
        }
        const float4* sr = (const float4*)(zs + (size_t)r * 16);
        const float4* sc = (const float4*)(zs + (size_t)c * 16);
        float ds = 0.0f;
        #pragma unroll
        for (int i = 0; i < 4; i++) {
            float4 a = sr[i], b = sc[i];
            ds += a.x * b.x + a.y * b.y + a.z * b.z + a.w * b.w;
        }
        pm += (double)w * (double)dm;
        ps += (double)w * (double)ds;
        if (r == c) psl += (double)w;
    }
    __shared__ double sm[NTHR / 64];
    double t;
    t = blk_reduce(pm, sm);  if (threadIdx.x == 0) atomicAdd(&acc[1], t);
    t = blk_reduce(ps, sm);  if (threadIdx.x == 0) atomicAdd(&acc[3], t);
    t = blk_reduce(psl, sm); if (threadIdx.x == 0) atomicAdd(&acc[4], t);
}

__global__ void final_kernel(const double* __restrict__ acc, const double* __restrict__ G,
                             float* __restrict__ out, int N, int D) {
    if (threadIdx.x != 0 || blockIdx.x != 0) return;
    // A = I + G (beta = 1), symmetric from upper-triangle storage
    double A[16][16];
    for (int i = 0; i < 16; i++)
        for (int j = i; j < 16; j++) {
            double v = G[i * 16 + j] + (i == j ? 1.0 : 0.0);
            A[i][j] = v; A[j][i] = v;
        }
    // Cholesky logdet
    double l1 = 0.0;
    for (int k = 0; k < 16; k++) {
        double d = A[k][k];
        for (int m = 0; m < k; m++) d -= A[k][m] * A[k][m];
        d = sqrt(d);
        l1 += 2.0 * log(d);
        A[k][k] = d;
        const double inv = 1.0 / d;
        for (int r = k + 1; r < 16; r++) {
            double s = A[r][k];
            for (int m = 0; m < k; m++) s -= A[r][m] * A[k][m];
            A[r][k] = s * inv;
        }
    }
    const double trace_L = (double)N - acc[4];
    const double l2 = (acc[2] - acc[3]) + trace_L;   // beta = 1
    const double l3 = acc[0] - acc[1];
    out[0] = (float)((l3 / (double)D + l2 - l1) / (2.0 * (double)N));
}

extern "C" void kernel_launch(void* const* d_in, const int* in_sizes, int n_in,
                              void* d_out, int out_size, void* d_ws, size_t ws_size,
                              hipStream_t stream) {
    const float* zm = (const float*)d_in[0];
    const float* zs = (const float*)d_in[1];
    const int*   ei = (const int*)d_in[2];

    const int N = in_sizes[0] / 32;   // D_MEAN = 32
    const int E = in_sizes[2] / 2;    // edge_index is [2, E]
    const int* row = ei;
    const int* col = ei + E;

    // ws layout: [deg: N int] [acc: 8 double][G: 256 double] [dinv: N float]
    char* ws = (char*)d_ws;
    int* deg = (int*)ws;
    size_t off1 = (((size_t)N * sizeof(int)) + 255) & ~(size_t)255;
    double* acc = (double*)(ws + off1);
    double* G   = acc + 8;
    size_t off2 = (off1 + 264 * sizeof(double) + 255) & ~(size_t)255;
    float* dinv = (float*)(ws + off2);

    // zero deg + accumulators (ws is poisoned 0xAA before every call)
    hipMemsetAsync(ws, 0, off1 + 264 * sizeof(double), stream);

    deg_kernel <<<1024, NTHR, 0, stream>>>(row, deg, E);
    dinv_kernel<<<512,  NTHR, 0, stream>>>(deg, dinv, N);
    ss_kernel  <<<512,  NTHR, 0, stream>>>(zm, zs, acc, N);
    gram_kernel<<<NPAIR * GCHUNK, NTHR, 0, stream>>>(zs, G, N);
    edge_kernel<<<1024, NTHR, 0, stream>>>(zm, zs, row, col, dinv, acc, E);
    final_kernel<<<1, 64, 0, stream>>>(acc, G, (float*)d_out, N, 32);
}

// Round 2
// 466.891 us; speedup vs baseline: 1.0723x; 1.0723x over previous
//
#include <hip/hip_runtime.h>
#include <math.h>

// GMRF sampling loss. Scalar output.
// N = 100000 nodes, E = 1.6M edges, D_MEAN = 32, RANK = 16, BETA = 1.0.
// R2: edge kernel uses 4-lane-per-edge coalesced gather (was 1 thread/edge,
//     latency-bound at 180us, VALUBusy 2.9%); gram kernel LDS-tiled (was a
//     12.5K-long dependent double-FMA chain per thread).

#define NTHR 256

__device__ __forceinline__ double blk_reduce(double v, double* sm) {
    #pragma unroll
    for (int o = 32; o > 0; o >>= 1) v += __shfl_down(v, o, 64);
    const int lane = threadIdx.x & 63;
    const int wid  = threadIdx.x >> 6;
    __syncthreads();
    if (lane == 0) sm[wid] = v;
    __syncthreads();
    double s = 0.0;
    if (threadIdx.x == 0) {
        const int nw = blockDim.x >> 6;
        for (int i = 0; i < nw; i++) s += sm[i];
    }
    return s;
}

__global__ void deg_kernel(const int* __restrict__ row, int* __restrict__ deg, int E) {
    for (int e = blockIdx.x * blockDim.x + threadIdx.x; e < E; e += gridDim.x * blockDim.x)
        atomicAdd(&deg[row[e]], 1);
}

__global__ void dinv_kernel(const int* __restrict__ deg, float* __restrict__ dinv, int N) {
    for (int n = blockIdx.x * blockDim.x + threadIdx.x; n < N; n += gridDim.x * blockDim.x) {
        int d = deg[n];
        dinv[n] = (d > 0) ? (float)(1.0 / sqrt((double)d)) : 0.0f;
    }
}

// acc layout: [0]=SS_mean [1]=S_edge_mean [2]=SS_std [3]=S_edge_std [4]=S_selfloop
__global__ void ss_kernel(const float* __restrict__ zm, const float* __restrict__ zs,
                          double* __restrict__ acc, int N) {
    double pm = 0.0, ps = 0.0;
    for (int n = blockIdx.x * blockDim.x + threadIdx.x; n < N; n += gridDim.x * blockDim.x) {
        const float4* a = (const float4*)(zm + (size_t)n * 32);
        #pragma unroll
        for (int i = 0; i < 8; i++) {
            float4 v = a[i];
            pm += (double)(v.x * v.x + v.y * v.y) + (double)(v.z * v.z + v.w * v.w);
        }
        const float4* b = (const float4*)(zs + (size_t)n * 16);
        #pragma unroll
        for (int i = 0; i < 4; i++) {
            float4 v = b[i];
            ps += (double)(v.x * v.x + v.y * v.y) + (double)(v.z * v.z + v.w * v.w);
        }
    }
    __shared__ double sm[NTHR / 64];
    double t;
    t = blk_reduce(pm, sm); if (threadIdx.x == 0) atomicAdd(&acc[0], t);
    t = blk_reduce(ps, sm); if (threadIdx.x == 0) atomicAdd(&acc[2], t);
}

// Gram 16x16 upper triangle (136 pairs). LDS-tiled: stage 256 rows coalesced,
// threads 0..135 each own one pair, fp32 per-tile accumulate -> double.
#define GBLK 128
__global__ void gram_kernel(const float* __restrict__ zs, double* __restrict__ G, int N) {
    __shared__ float tile[256 * 16];  // 16 KB
    int i = 0, j = 0;
    if (threadIdx.x < 136) {
        int pp = threadIdx.x;
        while (pp >= 16 - i) { pp -= 16 - i; i++; }
        j = i + pp;
    }
    const int rows_per_blk = (N + gridDim.x - 1) / gridDim.x;
    const int n0 = blockIdx.x * rows_per_blk;
    const int n1 = (n0 + rows_per_blk < N) ? n0 + rows_per_blk : N;
    double a = 0.0;
    for (int base = n0; base < n1; base += 256) {
        const int cnt = (n1 - base < 256) ? (n1 - base) : 256;
        __syncthreads();
        const float4* src = (const float4*)(zs + (size_t)base * 16);
        for (int idx = threadIdx.x; idx < cnt * 4; idx += blockDim.x)
            ((float4*)tile)[idx] = src[idx];
        __syncthreads();
        if (threadIdx.x < 136) {
            float f = 0.0f;
            for (int n = 0; n < cnt; n++)
                f += tile[n * 16 + i] * tile[n * 16 + j];
            a += (double)f;
        }
    }
    if (threadIdx.x < 136) atomicAdd(&G[i * 16 + j], a);
}

// 4 lanes per edge: lane k of a group loads float4 slices k and k+4 of the
// zm rows and slice k of the zs rows -> a wave's load instruction covers
// 16 coalesced 64B segments instead of 64 scattered 16B requests.
__global__ void edge_kernel(const float* __restrict__ zm, const float* __restrict__ zs,
                            const int* __restrict__ row, const int* __restrict__ col,
                            const float* __restrict__ dinv, double* __restrict__ acc, int E) {
    const int tid = blockIdx.x * blockDim.x + threadIdx.x;
    const int k = tid & 3;
    const int g0 = tid >> 2;
    const int ngroups = (gridDim.x * blockDim.x) >> 2;
    double pm_acc = 0.0, ps_acc = 0.0, psl = 0.0;
    for (int e = g0; e < E; e += ngroups) {
        const int r = row[e], c = col[e];
        const float4* ar = (const float4*)(zm + (size_t)r * 32);
        const float4* ac = (const float4*)(zm + (size_t)c * 32);
        const float4* sr = (const float4*)(zs + (size_t)r * 16);
        const float4* sc = (const float4*)(zs + (size_t)c * 16);
        float4 a0 = ar[k], b0 = ac[k], a1 = ar[k + 4], b1 = ac[k + 4];
        float4 s0 = sr[k], s1 = sc[k];
        float pm = a0.x * b0.x + a0.y * b0.y + a0.z * b0.z + a0.w * b0.w
                 + a1.x * b1.x + a1.y * b1.y + a1.z * b1.z + a1.w * b1.w;
        float ps = s0.x * s1.x + s0.y * s1.y + s0.z * s1.z + s0.w * s1.w;
        pm += __shfl_xor(pm, 1, 64);  ps += __shfl_xor(ps, 1, 64);
        pm += __shfl_xor(pm, 2, 64);  ps += __shfl_xor(ps, 2, 64);
        if (k == 0) {
            const float w = dinv[r] * dinv[c];
            pm_acc += (double)w * (double)pm;
            ps_acc += (double)w * (double)ps;
            if (r == c) psl += (double)w;
        }
    }
    __shared__ double sm[NTHR / 64];
    double t;
    t = blk_reduce(pm_acc, sm); if (threadIdx.x == 0) atomicAdd(&acc[1], t);
    t = blk_reduce(ps_acc, sm); if (threadIdx.x == 0) atomicAdd(&acc[3], t);
    t = blk_reduce(psl, sm);    if (threadIdx.x == 0) atomicAdd(&acc[4], t);
}

__global__ void final_kernel(const double* __restrict__ acc, const double* __restrict__ G,
                             float* __restrict__ out, int N, int D) {
    if (threadIdx.x != 0 || blockIdx.x != 0) return;
    double A[16][16];
    for (int i = 0; i < 16; i++)
        for (int j = i; j < 16; j++) {
            double v = G[i * 16 + j] + (i == j ? 1.0 : 0.0);
            A[i][j] = v; A[j][i] = v;
        }
    double l1 = 0.0;
    for (int k = 0; k < 16; k++) {
        double d = A[k][k];
        for (int m = 0; m < k; m++) d -= A[k][m] * A[k][m];
        d = sqrt(d);
        l1 += 2.0 * log(d);
        A[k][k] = d;
        const double inv = 1.0 / d;
        for (int r = k + 1; r < 16; r++) {
            double s = A[r][k];
            for (int m = 0; m < k; m++) s -= A[r][m] * A[k][m];
            A[r][k] = s * inv;
        }
    }
    const double trace_L = (double)N - acc[4];
    const double l2 = (acc[2] - acc[3]) + trace_L;
    const double l3 = acc[0] - acc[1];
    out[0] = (float)((l3 / (double)D + l2 - l1) / (2.0 * (double)N));
}

extern "C" void kernel_launch(void* const* d_in, const int* in_sizes, int n_in,
                              void* d_out, int out_size, void* d_ws, size_t ws_size,
                              hipStream_t stream) {
    const float* zm = (const float*)d_in[0];
    const float* zs = (const float*)d_in[1];
    const int*   ei = (const int*)d_in[2];

    const int N = in_sizes[0] / 32;
    const int E = in_sizes[2] / 2;
    const int* row = ei;
    const int* col = ei + E;

    // ws layout: [deg: N int] [acc: 8 double][G: 256 double] [dinv: N float]
    char* ws = (char*)d_ws;
    int* deg = (int*)ws;
    size_t off1 = (((size_t)N * sizeof(int)) + 255) & ~(size_t)255;
    double* acc = (double*)(ws + off1);
    double* G   = acc + 8;
    size_t off2 = (off1 + 264 * sizeof(double) + 255) & ~(size_t)255;
    float* dinv = (float*)(ws + off2);

    hipMemsetAsync(ws, 0, off1 + 264 * sizeof(double), stream);

    deg_kernel <<<1024, NTHR, 0, stream>>>(row, deg, E);
    dinv_kernel<<<512,  NTHR, 0, stream>>>(deg, dinv, N);
    ss_kernel  <<<512,  NTHR, 0, stream>>>(zm, zs, acc, N);
    gram_kernel<<<GBLK, NTHR, 0, stream>>>(zs, G, N);
    edge_kernel<<<4096, NTHR, 0, stream>>>(zm, zs, row, col, dinv, acc, E);
    final_kernel<<<1, 64, 0, stream>>>(acc, G, (float*)d_out, N, 32);
}

// Round 4
// 442.219 us; speedup vs baseline: 1.1321x; 1.0558x over previous
//
#include <hip/hip_runtime.h>
#include <math.h>

// GMRF sampling loss. Scalar output.
// N = 100000 nodes, E = 1.6M edges, D_MEAN = 32, RANK = 16, BETA = 1.0.
// R4: same as R3 (fp8-e4m3 packed gather rows, 64 B/node, dinv folded) but
//     fp8 pack builtin's `hi` operand made a template constant (ICE required).
// Exact terms (sum F^2, Gram, logdet) still computed from fp32 originals.

#define NTHR 256

typedef float v2f __attribute__((ext_vector_type(2)));

#if __has_builtin(__builtin_amdgcn_cvt_pk_f32_fp8) && __has_builtin(__builtin_amdgcn_cvt_pk_fp8_f32)
#define FP8_HW 1
#else
#define FP8_HW 0
#endif

// ---- fp8 e4m3fn software fallback (only compiled if builtins missing) ----
__device__ __forceinline__ float fp8_dec1(unsigned b) {
    const unsigned s = (b >> 7) & 1u, e = (b >> 3) & 0xFu, m = b & 7u;
    float mag;
    if (e == 0) mag = (float)m * 0.001953125f;                       // m * 2^-9
    else        mag = __uint_as_float(((e + 120u) << 23) | (m << 20));
    return s ? -mag : mag;
}
__device__ __forceinline__ unsigned fp8_enc1(float f) {
    const unsigned sign = (__float_as_uint(f) >> 24) & 0x80u;
    float a = fabsf(f);
    if (!(a >= 0.0009765625f)) return sign;                          // -> 0
    if (a >= 448.0f) return sign | 0x7Eu;
    if (a < 0.015625f) {                                             // denorm
        int q = (int)rintf(a * 512.0f);
        return sign | (unsigned)q;                                   // q==8 -> 0x08 == 2^-6
    }
    unsigned u = __float_as_uint(a);
    u += 0x7FFFFu + ((u >> 20) & 1u);                                // RNE to 3 bits
    const unsigned e8 = (u >> 23) - 120u;
    if (e8 >= 16u) return sign | 0x7Eu;
    return sign | (e8 << 3) | ((u >> 20) & 7u);
}
// --------------------------------------------------------------------------

template <bool HI>
__device__ __forceinline__ unsigned pk2_fp8(float a, float b, unsigned old) {
#if FP8_HW
    return (unsigned)__builtin_amdgcn_cvt_pk_fp8_f32(a, b, (int)old, HI);
#else
    const unsigned ins = fp8_enc1(a) | (fp8_enc1(b) << 8);
    return HI ? ((old & 0x0000FFFFu) | (ins << 16)) : ((old & 0xFFFF0000u) | ins);
#endif
}

__device__ __forceinline__ float dot4_fp8(unsigned a, unsigned b) {
#if FP8_HW
    v2f al = __builtin_amdgcn_cvt_pk_f32_fp8((int)a, false);
    v2f ah = __builtin_amdgcn_cvt_pk_f32_fp8((int)a, true);
    v2f bl = __builtin_amdgcn_cvt_pk_f32_fp8((int)b, false);
    v2f bh = __builtin_amdgcn_cvt_pk_f32_fp8((int)b, true);
    return al[0] * bl[0] + al[1] * bl[1] + ah[0] * bh[0] + ah[1] * bh[1];
#else
    return fp8_dec1(a & 0xFF) * fp8_dec1(b & 0xFF)
         + fp8_dec1((a >> 8) & 0xFF) * fp8_dec1((b >> 8) & 0xFF)
         + fp8_dec1((a >> 16) & 0xFF) * fp8_dec1((b >> 16) & 0xFF)
         + fp8_dec1(a >> 24) * fp8_dec1(b >> 24);
#endif
}

__device__ __forceinline__ float dot16_fp8(uint4 a, uint4 b) {
    return dot4_fp8(a.x, b.x) + dot4_fp8(a.y, b.y)
         + dot4_fp8(a.z, b.z) + dot4_fp8(a.w, b.w);
}

__device__ __forceinline__ double blk_reduce(double v, double* sm) {
    #pragma unroll
    for (int o = 32; o > 0; o >>= 1) v += __shfl_down(v, o, 64);
    const int lane = threadIdx.x & 63;
    const int wid  = threadIdx.x >> 6;
    __syncthreads();
    if (lane == 0) sm[wid] = v;
    __syncthreads();
    double s = 0.0;
    if (threadIdx.x == 0) {
        const int nw = blockDim.x >> 6;
        for (int i = 0; i < nw; i++) s += sm[i];
    }
    return s;
}

__global__ void deg_kernel(const int* __restrict__ row, int* __restrict__ deg, int E) {
    for (int e = blockIdx.x * blockDim.x + threadIdx.x; e < E; e += gridDim.x * blockDim.x)
        atomicAdd(&deg[row[e]], 1);
}

// acc: [0]=SS_mean [1]=S_edge_mean [2]=SS_std [3]=S_edge_std [4]=S_selfloop
// Packs node rows to fp8 (dinv folded) AND accumulates sum-of-squares terms.
__global__ void pack_ss_kernel(const float* __restrict__ zm, const float* __restrict__ zs,
                               const int* __restrict__ deg, unsigned char* __restrict__ pack,
                               double* __restrict__ acc, int N) {
    double pm = 0.0, ps = 0.0;
    for (int n = blockIdx.x * blockDim.x + threadIdx.x; n < N; n += gridDim.x * blockDim.x) {
        const int dg = deg[n];
        const float di = (dg > 0) ? (float)(1.0 / sqrt((double)dg)) : 0.0f;
        uint4 w[4];
        const float4* a = (const float4*)(zm + (size_t)n * 32);
        float sm = 0.0f;
        #pragma unroll
        for (int h = 0; h < 2; h++) {
            unsigned wd[4];
            #pragma unroll
            for (int q = 0; q < 4; q++) {
                float4 v = a[h * 4 + q];
                sm += v.x * v.x + v.y * v.y + v.z * v.z + v.w * v.w;
                unsigned t = pk2_fp8<false>(v.x * di, v.y * di, 0u);
                wd[q] = pk2_fp8<true>(v.z * di, v.w * di, t);
            }
            w[h] = make_uint4(wd[0], wd[1], wd[2], wd[3]);
        }
        const float4* b = (const float4*)(zs + (size_t)n * 16);
        float ss = 0.0f;
        {
            unsigned wd[4];
            #pragma unroll
            for (int q = 0; q < 4; q++) {
                float4 v = b[q];
                ss += v.x * v.x + v.y * v.y + v.z * v.z + v.w * v.w;
                unsigned t = pk2_fp8<false>(v.x * di, v.y * di, 0u);
                wd[q] = pk2_fp8<true>(v.z * di, v.w * di, t);
            }
            w[2] = make_uint4(wd[0], wd[1], wd[2], wd[3]);
        }
        w[3] = make_uint4(__float_as_uint(di), 0u, 0u, 0u);
        uint4* dst = (uint4*)(pack + (size_t)n * 64);
        dst[0] = w[0]; dst[1] = w[1]; dst[2] = w[2]; dst[3] = w[3];
        pm += (double)sm;
        ps += (double)ss;
    }
    __shared__ double smem[NTHR / 64];
    double t;
    t = blk_reduce(pm, smem); if (threadIdx.x == 0) atomicAdd(&acc[0], t);
    t = blk_reduce(ps, smem); if (threadIdx.x == 0) atomicAdd(&acc[2], t);
}

// Gram 16x16 upper triangle (136 pairs), LDS-tiled, from fp32 originals.
#define GBLK 256
__global__ void gram_kernel(const float* __restrict__ zs, double* __restrict__ G, int N) {
    __shared__ float tile[256 * 16];
    int i = 0, j = 0;
    if (threadIdx.x < 136) {
        int pp = threadIdx.x;
        while (pp >= 16 - i) { pp -= 16 - i; i++; }
        j = i + pp;
    }
    const int rows_per_blk = (N + gridDim.x - 1) / gridDim.x;
    const int n0 = blockIdx.x * rows_per_blk;
    const int n1 = (n0 + rows_per_blk < N) ? n0 + rows_per_blk : N;
    double a = 0.0;
    for (int base = n0; base < n1; base += 256) {
        const int cnt = (n1 - base < 256) ? (n1 - base) : 256;
        __syncthreads();
        const float4* src = (const float4*)(zs + (size_t)base * 16);
        for (int idx = threadIdx.x; idx < cnt * 4; idx += blockDim.x)
            ((float4*)tile)[idx] = src[idx];
        __syncthreads();
        if (threadIdx.x < 136) {
            float f = 0.0f;
            for (int n = 0; n < cnt; n++)
                f += tile[n * 16 + i] * tile[n * 16 + j];
            a += (double)f;
        }
    }
    if (threadIdx.x < 136) atomicAdd(&G[i * 16 + j], a);
}

// 4 lanes/edge. Lane k<3 loads 16B chunk k of packed rows r and c (all three
// chunks fall in the SAME 64B sector per endpoint -> 2 random sectors/edge).
__global__ void edge_fp8_kernel(const unsigned char* __restrict__ pack,
                                const int* __restrict__ row, const int* __restrict__ col,
                                double* __restrict__ acc, int E) {
    const int tid = blockIdx.x * blockDim.x + threadIdx.x;
    const int k = tid & 3;
    const int g0 = tid >> 2;
    const int ngroups = (gridDim.x * blockDim.x) >> 2;
    double pm_acc = 0.0, ps_acc = 0.0, psl = 0.0;
    for (int e = g0; e < E; e += ngroups) {
        const int r = row[e], c = col[e];
        float d = 0.0f;
        if (k < 3) {
            const uint4 qr = *(const uint4*)(pack + (size_t)r * 64 + k * 16);
            const uint4 qc = *(const uint4*)(pack + (size_t)c * 64 + k * 16);
            d = dot16_fp8(qr, qc);
        }
        const float dsum01 = d + __shfl_xor(d, 1, 64);   // lanes k=0,1: zm dot
        const float d2 = __shfl_xor(d, 2, 64);           // lane k=0: zs dot
        if (k == 0) {
            pm_acc += (double)dsum01;
            ps_acc += (double)d2;
            if (r == c) {                                 // ~E/N times total
                const float di = *(const float*)(pack + (size_t)r * 64 + 48);
                psl += (double)di * (double)di;
            }
        }
    }
    __shared__ double sm[NTHR / 64];
    double t;
    t = blk_reduce(pm_acc, sm); if (threadIdx.x == 0) atomicAdd(&acc[1], t);
    t = blk_reduce(ps_acc, sm); if (threadIdx.x == 0) atomicAdd(&acc[3], t);
    t = blk_reduce(psl, sm);    if (threadIdx.x == 0) atomicAdd(&acc[4], t);
}

__global__ void final_kernel(const double* __restrict__ acc, const double* __restrict__ G,
                             float* __restrict__ out, int N, int D) {
    if (threadIdx.x != 0 || blockIdx.x != 0) return;
    double A[16][16];
    for (int i = 0; i < 16; i++)
        for (int j = i; j < 16; j++) {
            double v = G[i * 16 + j] + (i == j ? 1.0 : 0.0);
            A[i][j] = v; A[j][i] = v;
        }
    double l1 = 0.0;
    for (int kk = 0; kk < 16; kk++) {
        double d = A[kk][kk];
        for (int m = 0; m < kk; m++) d -= A[kk][m] * A[kk][m];
        d = sqrt(d);
        l1 += 2.0 * log(d);
        A[kk][kk] = d;
        const double inv = 1.0 / d;
        for (int r = kk + 1; r < 16; r++) {
            double s = A[r][kk];
            for (int m = 0; m < kk; m++) s -= A[r][m] * A[kk][m];
            A[r][kk] = s * inv;
        }
    }
    const double trace_L = (double)N - acc[4];
    const double l2 = (acc[2] - acc[3]) + trace_L;
    const double l3 = acc[0] - acc[1];
    out[0] = (float)((l3 / (double)D + l2 - l1) / (2.0 * (double)N));
}

extern "C" void kernel_launch(void* const* d_in, const int* in_sizes, int n_in,
                              void* d_out, int out_size, void* d_ws, size_t ws_size,
                              hipStream_t stream) {
    const float* zm = (const float*)d_in[0];
    const float* zs = (const float*)d_in[1];
    const int*   ei = (const int*)d_in[2];

    const int N = in_sizes[0] / 32;
    const int E = in_sizes[2] / 2;
    const int* row = ei;
    const int* col = ei + E;

    // ws: [deg: N int] [acc: 8 dbl][G: 256 dbl] [pack: N*64 bytes]
    char* ws = (char*)d_ws;
    int* deg = (int*)ws;
    size_t off1 = (((size_t)N * sizeof(int)) + 255) & ~(size_t)255;
    double* acc = (double*)(ws + off1);
    double* G   = acc + 8;
    size_t off2 = (off1 + 264 * sizeof(double) + 255) & ~(size_t)255;
    unsigned char* pack = (unsigned char*)(ws + off2);

    (void)hipMemsetAsync(ws, 0, off1 + 264 * sizeof(double), stream);

    deg_kernel     <<<2048, NTHR, 0, stream>>>(row, deg, E);
    pack_ss_kernel <<<512,  NTHR, 0, stream>>>(zm, zs, deg, pack, acc, N);
    gram_kernel    <<<GBLK, NTHR, 0, stream>>>(zs, G, N);
    edge_fp8_kernel<<<4096, NTHR, 0, stream>>>(pack, row, col, acc, E);
    final_kernel   <<<1, 64, 0, stream>>>(acc, G, (float*)d_out, N, 32);
}

// Round 5
// 363.382 us; speedup vs baseline: 1.3777x; 1.2170x over previous
//
#include <hip/hip_runtime.h>
#include <math.h>

// GMRF sampling loss. Scalar output.
// N = 100000 nodes, E = 1.6M edges, D_MEAN = 32, RANK = 16, BETA = 1.0.
// R5: edge gather table shrunk to 32 B/node via int4 symmetric quantization
//     (per-node amax scale x dinv, bf16 scales in-row) -> 3.2 MB table fits
//     each 4 MiB XCD L2. R4 evidence: gather pinned at ~0.03 sector/cy/CU
//     regardless of bytes => outstanding-miss x ~900cy miss-latency bound;
//     L2 residency cuts latency to ~200cy. 1 thread/edge, 4 independent
//     16B loads, no shuffles.
// Exact terms (sum F^2, Gram, logdet) still computed from fp32 originals.

#define NTHR 256

__device__ __forceinline__ unsigned bf16_rne(float f) {
    unsigned u = __float_as_uint(f);
    u += 0x7FFFu + ((u >> 16) & 1u);
    return u >> 16;
}
__device__ __forceinline__ float bf16_dec(unsigned h) {
    return __uint_as_float(h << 16);
}

__device__ __forceinline__ double blk_reduce(double v, double* sm) {
    #pragma unroll
    for (int o = 32; o > 0; o >>= 1) v += __shfl_down(v, o, 64);
    const int lane = threadIdx.x & 63;
    const int wid  = threadIdx.x >> 6;
    __syncthreads();
    if (lane == 0) sm[wid] = v;
    __syncthreads();
    double s = 0.0;
    if (threadIdx.x == 0) {
        const int nw = blockDim.x >> 6;
        for (int i = 0; i < nw; i++) s += sm[i];
    }
    return s;
}

__global__ void deg_kernel(const int* __restrict__ row, int* __restrict__ deg, int E) {
    for (int e = blockIdx.x * blockDim.x + threadIdx.x; e < E; e += gridDim.x * blockDim.x)
        atomicAdd(&deg[row[e]], 1);
}

// acc: [0]=SS_mean [1]=S_edge_mean [2]=SS_std [3]=S_edge_std [4]=S_selfloop
// Packs each node to 32 B: [4dw zm int4x32][2dw zs int4x16][bf16 s_m|s_s][bf16 dinv|0]
// where s_m = (amax_m/7)*dinv, s_s = (amax_s/7)*dinv. Also accumulates exact
// sum-of-squares terms from the fp32 originals.
__global__ void pack_ss_kernel(const float* __restrict__ zm, const float* __restrict__ zs,
                               const int* __restrict__ deg, uint4* __restrict__ pack,
                               double* __restrict__ acc, int N) {
    double pm = 0.0, ps = 0.0;
    for (int n = blockIdx.x * blockDim.x + threadIdx.x; n < N; n += gridDim.x * blockDim.x) {
        const int dg = deg[n];
        const float di = (dg > 0) ? (float)(1.0 / sqrt((double)dg)) : 0.0f;

        float m[32], s[16];
        float sm = 0.0f, amx = 0.0f;
        const float4* a = (const float4*)(zm + (size_t)n * 32);
        #pragma unroll
        for (int i = 0; i < 8; i++) {
            float4 v = a[i];
            m[i * 4 + 0] = v.x; m[i * 4 + 1] = v.y; m[i * 4 + 2] = v.z; m[i * 4 + 3] = v.w;
            sm += v.x * v.x + v.y * v.y + v.z * v.z + v.w * v.w;
            amx = fmaxf(amx, fmaxf(fmaxf(fabsf(v.x), fabsf(v.y)), fmaxf(fabsf(v.z), fabsf(v.w))));
        }
        float ss = 0.0f, asx = 0.0f;
        const float4* b = (const float4*)(zs + (size_t)n * 16);
        #pragma unroll
        for (int i = 0; i < 4; i++) {
            float4 v = b[i];
            s[i * 4 + 0] = v.x; s[i * 4 + 1] = v.y; s[i * 4 + 2] = v.z; s[i * 4 + 3] = v.w;
            ss += v.x * v.x + v.y * v.y + v.z * v.z + v.w * v.w;
            asx = fmaxf(asx, fmaxf(fmaxf(fabsf(v.x), fabsf(v.y)), fmaxf(fabsf(v.z), fabsf(v.w))));
        }

        const float invm = (amx > 0.0f) ? 7.0f / amx : 0.0f;
        const float invs = (asx > 0.0f) ? 7.0f / asx : 0.0f;

        unsigned dw[8];
        #pragma unroll
        for (int d = 0; d < 4; d++) {
            unsigned w = 0;
            #pragma unroll
            for (int j = 0; j < 8; j++) {
                int q = __float2int_rn(m[d * 8 + j] * invm);
                q = max(-7, min(7, q));
                w |= ((unsigned)q & 15u) << (4 * j);
            }
            dw[d] = w;
        }
        #pragma unroll
        for (int d = 0; d < 2; d++) {
            unsigned w = 0;
            #pragma unroll
            for (int j = 0; j < 8; j++) {
                int q = __float2int_rn(s[d * 8 + j] * invs);
                q = max(-7, min(7, q));
                w |= ((unsigned)q & 15u) << (4 * j);
            }
            dw[4 + d] = w;
        }
        dw[6] = bf16_rne(amx * (1.0f / 7.0f) * di) | (bf16_rne(asx * (1.0f / 7.0f) * di) << 16);
        dw[7] = bf16_rne(di);

        pack[(size_t)n * 2 + 0] = make_uint4(dw[0], dw[1], dw[2], dw[3]);
        pack[(size_t)n * 2 + 1] = make_uint4(dw[4], dw[5], dw[6], dw[7]);

        pm += (double)sm;
        ps += (double)ss;
    }
    __shared__ double smem[NTHR / 64];
    double t;
    t = blk_reduce(pm, smem); if (threadIdx.x == 0) atomicAdd(&acc[0], t);
    t = blk_reduce(ps, smem); if (threadIdx.x == 0) atomicAdd(&acc[2], t);
}

// Gram 16x16 upper triangle (136 pairs), LDS-tiled, from fp32 originals.
#define GBLK 256
__global__ void gram_kernel(const float* __restrict__ zs, double* __restrict__ G, int N) {
    __shared__ float tile[256 * 16];
    int i = 0, j = 0;
    if (threadIdx.x < 136) {
        int pp = threadIdx.x;
        while (pp >= 16 - i) { pp -= 16 - i; i++; }
        j = i + pp;
    }
    const int rows_per_blk = (N + gridDim.x - 1) / gridDim.x;
    const int n0 = blockIdx.x * rows_per_blk;
    const int n1 = (n0 + rows_per_blk < N) ? n0 + rows_per_blk : N;
    double a = 0.0;
    for (int base = n0; base < n1; base += 256) {
        const int cnt = (n1 - base < 256) ? (n1 - base) : 256;
        __syncthreads();
        const float4* src = (const float4*)(zs + (size_t)base * 16);
        for (int idx = threadIdx.x; idx < cnt * 4; idx += blockDim.x)
            ((float4*)tile)[idx] = src[idx];
        __syncthreads();
        if (threadIdx.x < 136) {
            float f = 0.0f;
            for (int n = 0; n < cnt; n++)
                f += tile[n * 16 + i] * tile[n * 16 + j];
            a += (double)f;
        }
    }
    if (threadIdx.x < 136) atomicAdd(&G[i * 16 + j], a);
}

__device__ __forceinline__ int dot8_i4(unsigned a, unsigned b) {
    int acc = 0;
    #pragma unroll
    for (int j = 0; j < 8; j++) {
        const int x = ((int)(a << (28 - 4 * j))) >> 28;
        const int y = ((int)(b << (28 - 4 * j))) >> 28;
        acc += x * y;
    }
    return acc;
}

// 1 thread/edge. 4 independent 16B loads (1 sector per endpoint, 3.2 MB
// table -> XCD-L2 resident). No shuffles, no divergence except self-loops.
__global__ void edge_i4_kernel(const uint4* __restrict__ pack,
                               const int* __restrict__ row, const int* __restrict__ col,
                               double* __restrict__ acc, int E) {
    double pm = 0.0, ps = 0.0, psl = 0.0;
    for (int e = blockIdx.x * blockDim.x + threadIdx.x; e < E; e += gridDim.x * blockDim.x) {
        const int r = row[e], c = col[e];
        const uint4 r0 = pack[(size_t)r * 2 + 0];
        const uint4 r1 = pack[(size_t)r * 2 + 1];
        const uint4 c0 = pack[(size_t)c * 2 + 0];
        const uint4 c1 = pack[(size_t)c * 2 + 1];
        const int im = dot8_i4(r0.x, c0.x) + dot8_i4(r0.y, c0.y)
                     + dot8_i4(r0.z, c0.z) + dot8_i4(r0.w, c0.w);
        const int is = dot8_i4(r1.x, c1.x) + dot8_i4(r1.y, c1.y);
        const float smr = bf16_dec(r1.z & 0xFFFFu), ssr = bf16_dec(r1.z >> 16);
        const float smc = bf16_dec(c1.z & 0xFFFFu), ssc = bf16_dec(c1.z >> 16);
        pm += (double)((float)im * smr * smc);
        ps += (double)((float)is * ssr * ssc);
        if (r == c) {                                  // ~E/N times total
            const float d0 = bf16_dec(r1.w & 0xFFFFu);
            psl += (double)d0 * (double)d0;
        }
    }
    __shared__ double sm[NTHR / 64];
    double t;
    t = blk_reduce(pm, sm);  if (threadIdx.x == 0) atomicAdd(&acc[1], t);
    t = blk_reduce(ps, sm);  if (threadIdx.x == 0) atomicAdd(&acc[3], t);
    t = blk_reduce(psl, sm); if (threadIdx.x == 0) atomicAdd(&acc[4], t);
}

__global__ void final_kernel(const double* __restrict__ acc, const double* __restrict__ G,
                             float* __restrict__ out, int N, int D) {
    if (threadIdx.x != 0 || blockIdx.x != 0) return;
    double A[16][16];
    for (int i = 0; i < 16; i++)
        for (int j = i; j < 16; j++) {
            double v = G[i * 16 + j] + (i == j ? 1.0 : 0.0);
            A[i][j] = v; A[j][i] = v;
        }
    double l1 = 0.0;
    for (int kk = 0; kk < 16; kk++) {
        double d = A[kk][kk];
        for (int m = 0; m < kk; m++) d -= A[kk][m] * A[kk][m];
        d = sqrt(d);
        l1 += 2.0 * log(d);
        A[kk][kk] = d;
        const double inv = 1.0 / d;
        for (int r = kk + 1; r < 16; r++) {
            double s = A[r][kk];
            for (int m = 0; m < kk; m++) s -= A[r][m] * A[kk][m];
            A[r][kk] = s * inv;
        }
    }
    const double trace_L = (double)N - acc[4];
    const double l2 = (acc[2] - acc[3]) + trace_L;
    const double l3 = acc[0] - acc[1];
    out[0] = (float)((l3 / (double)D + l2 - l1) / (2.0 * (double)N));
}

extern "C" void kernel_launch(void* const* d_in, const int* in_sizes, int n_in,
                              void* d_out, int out_size, void* d_ws, size_t ws_size,
                              hipStream_t stream) {
    const float* zm = (const float*)d_in[0];
    const float* zs = (const float*)d_in[1];
    const int*   ei = (const int*)d_in[2];

    const int N = in_sizes[0] / 32;
    const int E = in_sizes[2] / 2;
    const int* row = ei;
    const int* col = ei + E;

    // ws: [deg: N int] [acc: 8 dbl][G: 256 dbl] [pack: N*32 bytes]
    char* ws = (char*)d_ws;
    int* deg = (int*)ws;
    size_t off1 = (((size_t)N * sizeof(int)) + 255) & ~(size_t)255;
    double* acc = (double*)(ws + off1);
    double* G   = acc + 8;
    size_t off2 = (off1 + 264 * sizeof(double) + 255) & ~(size_t)255;
    uint4* pack = (uint4*)(ws + off2);

    (void)hipMemsetAsync(ws, 0, off1 + 264 * sizeof(double), stream);

    deg_kernel    <<<2048, NTHR, 0, stream>>>(row, deg, E);
    pack_ss_kernel<<<512,  NTHR, 0, stream>>>(zm, zs, deg, pack, acc, N);
    gram_kernel   <<<GBLK, NTHR, 0, stream>>>(zs, G, N);
    edge_i4_kernel<<<2048, NTHR, 0, stream>>>(pack, row, col, acc, E);
    final_kernel  <<<1, 64, 0, stream>>>(acc, G, (float*)d_out, N, 32);
}

// Round 6
// 255.963 us; speedup vs baseline: 1.9559x; 1.4197x over previous
//
#include <hip/hip_runtime.h>
#include <math.h>

// GMRF sampling loss. Scalar output.
// N = 100000 nodes, E = 1.6M edges, D_MEAN = 32, RANK = 16, BETA = 1.0.
// R6: final_kernel Cholesky was 115us (top dispatch!) because double A[16][16]
//     with dynamic indexing lived in SCRATCH (~2700 dependent global-backed
//     accesses, VALUBusy 0.004%). Now fp32, fully unrolled (constant indices
//     -> registers), __launch_bounds__(64,1). A=I+G has diag ~1e5 vs offdiag
//     ~3e2 -> perfectly conditioned; l1 error ~1e-3 -> ~5e-9 in output.
// R5 (kept): int4-packed 32 B/node gather table, XCD-L2 resident.

#define NTHR 256

__device__ __forceinline__ unsigned bf16_rne(float f) {
    unsigned u = __float_as_uint(f);
    u += 0x7FFFu + ((u >> 16) & 1u);
    return u >> 16;
}
__device__ __forceinline__ float bf16_dec(unsigned h) {
    return __uint_as_float(h << 16);
}

__device__ __forceinline__ double blk_reduce(double v, double* sm) {
    #pragma unroll
    for (int o = 32; o > 0; o >>= 1) v += __shfl_down(v, o, 64);
    const int lane = threadIdx.x & 63;
    const int wid  = threadIdx.x >> 6;
    __syncthreads();
    if (lane == 0) sm[wid] = v;
    __syncthreads();
    double s = 0.0;
    if (threadIdx.x == 0) {
        const int nw = blockDim.x >> 6;
        for (int i = 0; i < nw; i++) s += sm[i];
    }
    return s;
}

__global__ void deg_kernel(const int* __restrict__ row, int* __restrict__ deg, int E) {
    for (int e = blockIdx.x * blockDim.x + threadIdx.x; e < E; e += gridDim.x * blockDim.x)
        atomicAdd(&deg[row[e]], 1);
}

// acc: [0]=SS_mean [1]=S_edge_mean [2]=SS_std [3]=S_edge_std [4]=S_selfloop
__global__ void pack_ss_kernel(const float* __restrict__ zm, const float* __restrict__ zs,
                               const int* __restrict__ deg, uint4* __restrict__ pack,
                               double* __restrict__ acc, int N) {
    double pm = 0.0, ps = 0.0;
    for (int n = blockIdx.x * blockDim.x + threadIdx.x; n < N; n += gridDim.x * blockDim.x) {
        const int dg = deg[n];
        const float di = (dg > 0) ? (float)(1.0 / sqrt((double)dg)) : 0.0f;

        float m[32], s[16];
        float sm = 0.0f, amx = 0.0f;
        const float4* a = (const float4*)(zm + (size_t)n * 32);
        #pragma unroll
        for (int i = 0; i < 8; i++) {
            float4 v = a[i];
            m[i * 4 + 0] = v.x; m[i * 4 + 1] = v.y; m[i * 4 + 2] = v.z; m[i * 4 + 3] = v.w;
            sm += v.x * v.x + v.y * v.y + v.z * v.z + v.w * v.w;
            amx = fmaxf(amx, fmaxf(fmaxf(fabsf(v.x), fabsf(v.y)), fmaxf(fabsf(v.z), fabsf(v.w))));
        }
        float ss = 0.0f, asx = 0.0f;
        const float4* b = (const float4*)(zs + (size_t)n * 16);
        #pragma unroll
        for (int i = 0; i < 4; i++) {
            float4 v = b[i];
            s[i * 4 + 0] = v.x; s[i * 4 + 1] = v.y; s[i * 4 + 2] = v.z; s[i * 4 + 3] = v.w;
            ss += v.x * v.x + v.y * v.y + v.z * v.z + v.w * v.w;
            asx = fmaxf(asx, fmaxf(fmaxf(fabsf(v.x), fabsf(v.y)), fmaxf(fabsf(v.z), fabsf(v.w))));
        }

        const float invm = (amx > 0.0f) ? 7.0f / amx : 0.0f;
        const float invs = (asx > 0.0f) ? 7.0f / asx : 0.0f;

        unsigned dw[8];
        #pragma unroll
        for (int d = 0; d < 4; d++) {
            unsigned w = 0;
            #pragma unroll
            for (int j = 0; j < 8; j++) {
                int q = __float2int_rn(m[d * 8 + j] * invm);
                q = max(-7, min(7, q));
                w |= ((unsigned)q & 15u) << (4 * j);
            }
            dw[d] = w;
        }
        #pragma unroll
        for (int d = 0; d < 2; d++) {
            unsigned w = 0;
            #pragma unroll
            for (int j = 0; j < 8; j++) {
                int q = __float2int_rn(s[d * 8 + j] * invs);
                q = max(-7, min(7, q));
                w |= ((unsigned)q & 15u) << (4 * j);
            }
            dw[4 + d] = w;
        }
        dw[6] = bf16_rne(amx * (1.0f / 7.0f) * di) | (bf16_rne(asx * (1.0f / 7.0f) * di) << 16);
        dw[7] = bf16_rne(di);

        pack[(size_t)n * 2 + 0] = make_uint4(dw[0], dw[1], dw[2], dw[3]);
        pack[(size_t)n * 2 + 1] = make_uint4(dw[4], dw[5], dw[6], dw[7]);

        pm += (double)sm;
        ps += (double)ss;
    }
    __shared__ double smem[NTHR / 64];
    double t;
    t = blk_reduce(pm, smem); if (threadIdx.x == 0) atomicAdd(&acc[0], t);
    t = blk_reduce(ps, smem); if (threadIdx.x == 0) atomicAdd(&acc[2], t);
}

// Gram 16x16 upper triangle (136 pairs), LDS-tiled, from fp32 originals.
#define GBLK 256
__global__ void gram_kernel(const float* __restrict__ zs, double* __restrict__ G, int N) {
    __shared__ float tile[256 * 16];
    int i = 0, j = 0;
    if (threadIdx.x < 136) {
        int pp = threadIdx.x;
        while (pp >= 16 - i) { pp -= 16 - i; i++; }
        j = i + pp;
    }
    const int rows_per_blk = (N + gridDim.x - 1) / gridDim.x;
    const int n0 = blockIdx.x * rows_per_blk;
    const int n1 = (n0 + rows_per_blk < N) ? n0 + rows_per_blk : N;
    double a = 0.0;
    for (int base = n0; base < n1; base += 256) {
        const int cnt = (n1 - base < 256) ? (n1 - base) : 256;
        __syncthreads();
        const float4* src = (const float4*)(zs + (size_t)base * 16);
        for (int idx = threadIdx.x; idx < cnt * 4; idx += blockDim.x)
            ((float4*)tile)[idx] = src[idx];
        __syncthreads();
        if (threadIdx.x < 136) {
            float f = 0.0f;
            for (int n = 0; n < cnt; n++)
                f += tile[n * 16 + i] * tile[n * 16 + j];
            a += (double)f;
        }
    }
    if (threadIdx.x < 136) atomicAdd(&G[i * 16 + j], a);
}

__device__ __forceinline__ int dot8_i4(unsigned a, unsigned b) {
    int acc = 0;
    #pragma unroll
    for (int j = 0; j < 8; j++) {
        const int x = ((int)(a << (28 - 4 * j))) >> 28;
        const int y = ((int)(b << (28 - 4 * j))) >> 28;
        acc += x * y;
    }
    return acc;
}

// 1 thread/edge. 2x16B loads per endpoint (1 sector), table XCD-L2 resident.
__global__ void edge_i4_kernel(const uint4* __restrict__ pack,
                               const int* __restrict__ row, const int* __restrict__ col,
                               double* __restrict__ acc, int E) {
    double pm = 0.0, ps = 0.0, psl = 0.0;
    for (int e = blockIdx.x * blockDim.x + threadIdx.x; e < E; e += gridDim.x * blockDim.x) {
        const int r = row[e], c = col[e];
        const uint4 r0 = pack[(size_t)r * 2 + 0];
        const uint4 r1 = pack[(size_t)r * 2 + 1];
        const uint4 c0 = pack[(size_t)c * 2 + 0];
        const uint4 c1 = pack[(size_t)c * 2 + 1];
        const int im = dot8_i4(r0.x, c0.x) + dot8_i4(r0.y, c0.y)
                     + dot8_i4(r0.z, c0.z) + dot8_i4(r0.w, c0.w);
        const int is = dot8_i4(r1.x, c1.x) + dot8_i4(r1.y, c1.y);
        const float smr = bf16_dec(r1.z & 0xFFFFu), ssr = bf16_dec(r1.z >> 16);
        const float smc = bf16_dec(c1.z & 0xFFFFu), ssc = bf16_dec(c1.z >> 16);
        pm += (double)((float)im * smr * smc);
        ps += (double)((float)is * ssr * ssc);
        if (r == c) {
            const float d0 = bf16_dec(r1.w & 0xFFFFu);
            psl += (double)d0 * (double)d0;
        }
    }
    __shared__ double sm[NTHR / 64];
    double t;
    t = blk_reduce(pm, sm);  if (threadIdx.x == 0) atomicAdd(&acc[1], t);
    t = blk_reduce(ps, sm);  if (threadIdx.x == 0) atomicAdd(&acc[3], t);
    t = blk_reduce(psl, sm); if (threadIdx.x == 0) atomicAdd(&acc[4], t);
}

// Fully-unrolled fp32 Cholesky: every index compile-time constant -> A lives
// in VGPRs, zero scratch. Single wave; __launch_bounds__(64,1) frees the
// register budget.
__global__ void __launch_bounds__(64, 1)
final_kernel(const double* __restrict__ acc, const double* __restrict__ G,
             float* __restrict__ out, int N, int D) {
    if (threadIdx.x != 0 || blockIdx.x != 0) return;
    float A[16][16];
    #pragma unroll
    for (int i = 0; i < 16; i++)
        #pragma unroll
        for (int j = 0; j < 16; j++) {
            const int lo = (i < j) ? i : j, hi = (i < j) ? j : i;
            A[i][j] = (float)G[lo * 16 + hi] + (i == j ? 1.0f : 0.0f);
        }
    float l1 = 0.0f;
    #pragma unroll
    for (int k = 0; k < 16; k++) {
        float d = A[k][k];
        #pragma unroll
        for (int m = 0; m < 16; m++) if (m < k) d -= A[k][m] * A[k][m];
        d = sqrtf(d);
        l1 += 2.0f * logf(d);
        A[k][k] = d;
        const float inv = 1.0f / d;
        #pragma unroll
        for (int r = 0; r < 16; r++) if (r > k) {
            float s = A[r][k];
            #pragma unroll
            for (int m = 0; m < 16; m++) if (m < k) s -= A[r][m] * A[k][m];
            A[r][k] = s * inv;
        }
    }
    const double trace_L = (double)N - acc[4];
    const double l2 = (acc[2] - acc[3]) + trace_L;
    const double l3 = acc[0] - acc[1];
    out[0] = (float)((l3 / (double)D + l2 - (double)l1) / (2.0 * (double)N));
}

extern "C" void kernel_launch(void* const* d_in, const int* in_sizes, int n_in,
                              void* d_out, int out_size, void* d_ws, size_t ws_size,
                              hipStream_t stream) {
    const float* zm = (const float*)d_in[0];
    const float* zs = (const float*)d_in[1];
    const int*   ei = (const int*)d_in[2];

    const int N = in_sizes[0] / 32;
    const int E = in_sizes[2] / 2;
    const int* row = ei;
    const int* col = ei + E;

    // ws: [deg: N int] [acc: 8 dbl][G: 256 dbl] [pack: N*32 bytes]
    char* ws = (char*)d_ws;
    int* deg = (int*)ws;
    size_t off1 = (((size_t)N * sizeof(int)) + 255) & ~(size_t)255;
    double* acc = (double*)(ws + off1);
    double* G   = acc + 8;
    size_t off2 = (off1 + 264 * sizeof(double) + 255) & ~(size_t)255;
    uint4* pack = (uint4*)(ws + off2);

    (void)hipMemsetAsync(ws, 0, off1 + 264 * sizeof(double), stream);

    deg_kernel    <<<2048, NTHR, 0, stream>>>(row, deg, E);
    pack_ss_kernel<<<512,  NTHR, 0, stream>>>(zm, zs, deg, pack, acc, N);
    gram_kernel   <<<GBLK, NTHR, 0, stream>>>(zs, G, N);
    edge_i4_kernel<<<2048, NTHR, 0, stream>>>(pack, row, col, acc, E);
    final_kernel  <<<1, 64, 0, stream>>>(acc, G, (float*)d_out, N, 32);
}

// Round 7
// 247.751 us; speedup vs baseline: 2.0208x; 1.0331x over previous
//
#include <hip/hip_runtime.h>
#include <math.h>

// GMRF sampling loss. Scalar output.
// N = 100000 nodes, E = 1.6M edges, D_MEAN = 32, RANK = 16, BETA = 1.0.
// R7: edge kernel batches 4 edges/thread, issuing all 16 pack loads before
//     compute (MLP 4 -> 16). R6 evidence: table is L2-resident (FETCH 19MB)
//     but VALUBusy 9.5% / HBM 2.8% -> bound by L2-hit latency x outstanding
//     requests, not bytes or VALU.
// R6 (kept): fully-unrolled register Cholesky. R5 (kept): int4 32 B/node
// gather table, XCD-L2 resident.

#define NTHR 256

__device__ __forceinline__ unsigned bf16_rne(float f) {
    unsigned u = __float_as_uint(f);
    u += 0x7FFFu + ((u >> 16) & 1u);
    return u >> 16;
}
__device__ __forceinline__ float bf16_dec(unsigned h) {
    return __uint_as_float(h << 16);
}

__device__ __forceinline__ double blk_reduce(double v, double* sm) {
    #pragma unroll
    for (int o = 32; o > 0; o >>= 1) v += __shfl_down(v, o, 64);
    const int lane = threadIdx.x & 63;
    const int wid  = threadIdx.x >> 6;
    __syncthreads();
    if (lane == 0) sm[wid] = v;
    __syncthreads();
    double s = 0.0;
    if (threadIdx.x == 0) {
        const int nw = blockDim.x >> 6;
        for (int i = 0; i < nw; i++) s += sm[i];
    }
    return s;
}

__global__ void deg_kernel(const int* __restrict__ row, int* __restrict__ deg, int E) {
    for (int e = blockIdx.x * blockDim.x + threadIdx.x; e < E; e += gridDim.x * blockDim.x)
        atomicAdd(&deg[row[e]], 1);
}

// acc: [0]=SS_mean [1]=S_edge_mean [2]=SS_std [3]=S_edge_std [4]=S_selfloop
__global__ void pack_ss_kernel(const float* __restrict__ zm, const float* __restrict__ zs,
                               const int* __restrict__ deg, uint4* __restrict__ pack,
                               double* __restrict__ acc, int N) {
    double pm = 0.0, ps = 0.0;
    for (int n = blockIdx.x * blockDim.x + threadIdx.x; n < N; n += gridDim.x * blockDim.x) {
        const int dg = deg[n];
        const float di = (dg > 0) ? (float)(1.0 / sqrt((double)dg)) : 0.0f;

        float m[32], s[16];
        float sm = 0.0f, amx = 0.0f;
        const float4* a = (const float4*)(zm + (size_t)n * 32);
        #pragma unroll
        for (int i = 0; i < 8; i++) {
            float4 v = a[i];
            m[i * 4 + 0] = v.x; m[i * 4 + 1] = v.y; m[i * 4 + 2] = v.z; m[i * 4 + 3] = v.w;
            sm += v.x * v.x + v.y * v.y + v.z * v.z + v.w * v.w;
            amx = fmaxf(amx, fmaxf(fmaxf(fabsf(v.x), fabsf(v.y)), fmaxf(fabsf(v.z), fabsf(v.w))));
        }
        float ss = 0.0f, asx = 0.0f;
        const float4* b = (const float4*)(zs + (size_t)n * 16);
        #pragma unroll
        for (int i = 0; i < 4; i++) {
            float4 v = b[i];
            s[i * 4 + 0] = v.x; s[i * 4 + 1] = v.y; s[i * 4 + 2] = v.z; s[i * 4 + 3] = v.w;
            ss += v.x * v.x + v.y * v.y + v.z * v.z + v.w * v.w;
            asx = fmaxf(asx, fmaxf(fmaxf(fabsf(v.x), fabsf(v.y)), fmaxf(fabsf(v.z), fabsf(v.w))));
        }

        const float invm = (amx > 0.0f) ? 7.0f / amx : 0.0f;
        const float invs = (asx > 0.0f) ? 7.0f / asx : 0.0f;

        unsigned dw[8];
        #pragma unroll
        for (int d = 0; d < 4; d++) {
            unsigned w = 0;
            #pragma unroll
            for (int j = 0; j < 8; j++) {
                int q = __float2int_rn(m[d * 8 + j] * invm);
                q = max(-7, min(7, q));
                w |= ((unsigned)q & 15u) << (4 * j);
            }
            dw[d] = w;
        }
        #pragma unroll
        for (int d = 0; d < 2; d++) {
            unsigned w = 0;
            #pragma unroll
            for (int j = 0; j < 8; j++) {
                int q = __float2int_rn(s[d * 8 + j] * invs);
                q = max(-7, min(7, q));
                w |= ((unsigned)q & 15u) << (4 * j);
            }
            dw[4 + d] = w;
        }
        dw[6] = bf16_rne(amx * (1.0f / 7.0f) * di) | (bf16_rne(asx * (1.0f / 7.0f) * di) << 16);
        dw[7] = bf16_rne(di);

        pack[(size_t)n * 2 + 0] = make_uint4(dw[0], dw[1], dw[2], dw[3]);
        pack[(size_t)n * 2 + 1] = make_uint4(dw[4], dw[5], dw[6], dw[7]);

        pm += (double)sm;
        ps += (double)ss;
    }
    __shared__ double smem[NTHR / 64];
    double t;
    t = blk_reduce(pm, smem); if (threadIdx.x == 0) atomicAdd(&acc[0], t);
    t = blk_reduce(ps, smem); if (threadIdx.x == 0) atomicAdd(&acc[2], t);
}

// Gram 16x16 upper triangle (136 pairs), LDS-tiled, from fp32 originals.
// (Same-word LDS reads broadcast -> conflict-free; 512 blocks for spread.)
#define GBLK 512
__global__ void gram_kernel(const float* __restrict__ zs, double* __restrict__ G, int N) {
    __shared__ float tile[256 * 16];
    int i = 0, j = 0;
    if (threadIdx.x < 136) {
        int pp = threadIdx.x;
        while (pp >= 16 - i) { pp -= 16 - i; i++; }
        j = i + pp;
    }
    const int rows_per_blk = (N + gridDim.x - 1) / gridDim.x;
    const int n0 = blockIdx.x * rows_per_blk;
    const int n1 = (n0 + rows_per_blk < N) ? n0 + rows_per_blk : N;
    double a = 0.0;
    for (int base = n0; base < n1; base += 256) {
        const int cnt = (n1 - base < 256) ? (n1 - base) : 256;
        __syncthreads();
        const float4* src = (const float4*)(zs + (size_t)base * 16);
        for (int idx = threadIdx.x; idx < cnt * 4; idx += blockDim.x)
            ((float4*)tile)[idx] = src[idx];
        __syncthreads();
        if (threadIdx.x < 136) {
            float f = 0.0f;
            for (int n = 0; n < cnt; n++)
                f += tile[n * 16 + i] * tile[n * 16 + j];
            a += (double)f;
        }
    }
    if (threadIdx.x < 136) atomicAdd(&G[i * 16 + j], a);
}

__device__ __forceinline__ int dot8_i4(unsigned a, unsigned b) {
    int acc = 0;
    #pragma unroll
    for (int j = 0; j < 8; j++) {
        const int x = ((int)(a << (28 - 4 * j))) >> 28;
        const int y = ((int)(b << (28 - 4 * j))) >> 28;
        acc += x * y;
    }
    return acc;
}

// 4 edges/thread: int4-vectorized index loads, all 16 pack loads issued into
// register arrays before compute (MLP 16/thread). Table XCD-L2 resident.
__global__ void edge_i4_kernel(const uint4* __restrict__ pack,
                               const int* __restrict__ row, const int* __restrict__ col,
                               double* __restrict__ acc, int E) {
    double pm = 0.0, ps = 0.0, psl = 0.0;
    const int tid = blockIdx.x * blockDim.x + threadIdx.x;
    const int nthr = gridDim.x * blockDim.x;
    for (int q = tid; q * 4 < E; q += nthr) {
        const int e = q * 4;
        if (e + 4 <= E) {
            const int4 rr = *(const int4*)(row + e);
            const int4 cc = *(const int4*)(col + e);
            const int ri[4] = {rr.x, rr.y, rr.z, rr.w};
            const int ci[4] = {cc.x, cc.y, cc.z, cc.w};
            uint4 R0[4], R1[4], C0[4], C1[4];
            #pragma unroll
            for (int t = 0; t < 4; t++) {
                R0[t] = pack[(size_t)ri[t] * 2 + 0];
                R1[t] = pack[(size_t)ri[t] * 2 + 1];
                C0[t] = pack[(size_t)ci[t] * 2 + 0];
                C1[t] = pack[(size_t)ci[t] * 2 + 1];
            }
            float fpm = 0.0f, fps = 0.0f;
            #pragma unroll
            for (int t = 0; t < 4; t++) {
                const int im = dot8_i4(R0[t].x, C0[t].x) + dot8_i4(R0[t].y, C0[t].y)
                             + dot8_i4(R0[t].z, C0[t].z) + dot8_i4(R0[t].w, C0[t].w);
                const int is = dot8_i4(R1[t].x, C1[t].x) + dot8_i4(R1[t].y, C1[t].y);
                const float smr = bf16_dec(R1[t].z & 0xFFFFu), ssr = bf16_dec(R1[t].z >> 16);
                const float smc = bf16_dec(C1[t].z & 0xFFFFu), ssc = bf16_dec(C1[t].z >> 16);
                fpm += (float)im * smr * smc;
                fps += (float)is * ssr * ssc;
                if (ri[t] == ci[t]) {
                    const float d0 = bf16_dec(R1[t].w & 0xFFFFu);
                    psl += (double)d0 * (double)d0;
                }
            }
            pm += (double)fpm;
            ps += (double)fps;
        } else {
            for (int t = e; t < E; t++) {
                const int r = row[t], c = col[t];
                const uint4 r0 = pack[(size_t)r * 2 + 0];
                const uint4 r1 = pack[(size_t)r * 2 + 1];
                const uint4 c0 = pack[(size_t)c * 2 + 0];
                const uint4 c1 = pack[(size_t)c * 2 + 1];
                const int im = dot8_i4(r0.x, c0.x) + dot8_i4(r0.y, c0.y)
                             + dot8_i4(r0.z, c0.z) + dot8_i4(r0.w, c0.w);
                const int is = dot8_i4(r1.x, c1.x) + dot8_i4(r1.y, c1.y);
                const float smr = bf16_dec(r1.z & 0xFFFFu), ssr = bf16_dec(r1.z >> 16);
                const float smc = bf16_dec(c1.z & 0xFFFFu), ssc = bf16_dec(c1.z >> 16);
                pm += (double)((float)im * smr * smc);
                ps += (double)((float)is * ssr * ssc);
                if (r == c) {
                    const float d0 = bf16_dec(r1.w & 0xFFFFu);
                    psl += (double)d0 * (double)d0;
                }
            }
        }
    }
    __shared__ double sm[NTHR / 64];
    double t;
    t = blk_reduce(pm, sm);  if (threadIdx.x == 0) atomicAdd(&acc[1], t);
    t = blk_reduce(ps, sm);  if (threadIdx.x == 0) atomicAdd(&acc[3], t);
    t = blk_reduce(psl, sm); if (threadIdx.x == 0) atomicAdd(&acc[4], t);
}

// Fully-unrolled fp32 register Cholesky (no scratch).
__global__ void __launch_bounds__(64, 1)
final_kernel(const double* __restrict__ acc, const double* __restrict__ G,
             float* __restrict__ out, int N, int D) {
    if (threadIdx.x != 0 || blockIdx.x != 0) return;
    float A[16][16];
    #pragma unroll
    for (int i = 0; i < 16; i++)
        #pragma unroll
        for (int j = 0; j < 16; j++) {
            const int lo = (i < j) ? i : j, hi = (i < j) ? j : i;
            A[i][j] = (float)G[lo * 16 + hi] + (i == j ? 1.0f : 0.0f);
        }
    float l1 = 0.0f;
    #pragma unroll
    for (int k = 0; k < 16; k++) {
        float d = A[k][k];
        #pragma unroll
        for (int m = 0; m < 16; m++) if (m < k) d -= A[k][m] * A[k][m];
        d = sqrtf(d);
        l1 += 2.0f * logf(d);
        A[k][k] = d;
        const float inv = 1.0f / d;
        #pragma unroll
        for (int r = 0; r < 16; r++) if (r > k) {
            float s = A[r][k];
            #pragma unroll
            for (int m = 0; m < 16; m++) if (m < k) s -= A[r][m] * A[k][m];
            A[r][k] = s * inv;
        }
    }
    const double trace_L = (double)N - acc[4];
    const double l2 = (acc[2] - acc[3]) + trace_L;
    const double l3 = acc[0] - acc[1];
    out[0] = (float)((l3 / (double)D + l2 - (double)l1) / (2.0 * (double)N));
}

extern "C" void kernel_launch(void* const* d_in, const int* in_sizes, int n_in,
                              void* d_out, int out_size, void* d_ws, size_t ws_size,
                              hipStream_t stream) {
    const float* zm = (const float*)d_in[0];
    const float* zs = (const float*)d_in[1];
    const int*   ei = (const int*)d_in[2];

    const int N = in_sizes[0] / 32;
    const int E = in_sizes[2] / 2;
    const int* row = ei;
    const int* col = ei + E;

    // ws: [deg: N int] [acc: 8 dbl][G: 256 dbl] [pack: N*32 bytes]
    char* ws = (char*)d_ws;
    int* deg = (int*)ws;
    size_t off1 = (((size_t)N * sizeof(int)) + 255) & ~(size_t)255;
    double* acc = (double*)(ws + off1);
    double* G   = acc + 8;
    size_t off2 = (off1 + 264 * sizeof(double) + 255) & ~(size_t)255;
    uint4* pack = (uint4*)(ws + off2);

    (void)hipMemsetAsync(ws, 0, off1 + 264 * sizeof(double), stream);

    deg_kernel    <<<2048, NTHR, 0, stream>>>(row, deg, E);
    pack_ss_kernel<<<512,  NTHR, 0, stream>>>(zm, zs, deg, pack, acc, N);
    gram_kernel   <<<GBLK, NTHR, 0, stream>>>(zs, G, N);
    edge_i4_kernel<<<1600, NTHR, 0, stream>>>(pack, row, col, acc, E);
    final_kernel  <<<1, 64, 0, stream>>>(acc, G, (float*)d_out, N, 32);
}